// Round 19
// baseline (209.551 us; speedup 1.0000x reference)
//
#include <hip/hip_runtime.h>
#include <hip/hip_bf16.h>
#include <math.h>

// ---------------------------------------------------------------------------
// GCN(2 layers, fused norm) -> mean-pool -> LSTM step (h0=c0=0) -> heads
// GEMMs via bf16 MFMA (f32 accum). Gather buffer fp8-e4m3 (HW cvt), h bf16,
// all accumulation f32. Single-array CSR cursor (rowcur -> end pointers).
// 10 stream-ordered launches (cooperative grid.sync measured 4-6x worse).
// ---------------------------------------------------------------------------

#define POOL_SUB 32

#if __has_builtin(__builtin_amdgcn_cvt_pk_f32_fp8) && __has_builtin(__builtin_amdgcn_cvt_pk_fp8_f32)
#define USE_FP8 1
#else
#define USE_FP8 0
#endif

typedef __attribute__((ext_vector_type(8))) short bf16x8;
typedef __attribute__((ext_vector_type(4))) float f32x4;
typedef __attribute__((ext_vector_type(2))) float f32x2;

static __device__ __forceinline__ unsigned short f2bf(float f) {
    union { float f; unsigned int u; } v; v.f = f;
    unsigned int u = v.u;
    unsigned int r = u + 0x7FFFu + ((u >> 16) & 1u);  // RNE
    return (unsigned short)(r >> 16);
}
static __device__ __forceinline__ unsigned int pack2bf(float lo, float hi) {
    return (unsigned int)f2bf(lo) | ((unsigned int)f2bf(hi) << 16);
}
static __device__ __forceinline__ float bflo(unsigned int v) {
    union { unsigned int u; float f; } w; w.u = v << 16; return w.f;
}
static __device__ __forceinline__ float bfhi(unsigned int v) {
    union { unsigned int u; float f; } w; w.u = v & 0xFFFF0000u; return w.f;
}
static __device__ __forceinline__ bf16x8 f8_to_bf(float4 f0, float4 f1) {
    union { unsigned int u[4]; bf16x8 v; } r;
    r.u[0] = pack2bf(f0.x, f0.y);
    r.u[1] = pack2bf(f0.z, f0.w);
    r.u[2] = pack2bf(f1.x, f1.y);
    r.u[3] = pack2bf(f1.z, f1.w);
    return r.v;
}
#if USE_FP8
static __device__ __forceinline__ unsigned char f2fp8(float f) {
    return (unsigned char)(__builtin_amdgcn_cvt_pk_fp8_f32(f, f, 0, false) & 0xFF);
}
#endif

// blocks [0,zb): zero deg; blocks [zb,zb+128): W1/W2 -> bf16 transposed
__global__ __launch_bounds__(256) void prep_kernel(int* __restrict__ zp, int zwords,
                                                   const float* __restrict__ W1,
                                                   const float* __restrict__ W2,
                                                   unsigned short* __restrict__ Wt1,
                                                   unsigned short* __restrict__ Wt2, int zb) {
    int b = blockIdx.x;
    int t = threadIdx.x;
    if (b < zb) {
        int i = b * 256 + t;
        if (i < zwords) zp[i] = 0;
    } else {
        int col = b - zb;  // 0..127
        if (t < 128) Wt1[col * 128 + t] = f2bf(W1[(size_t)t * 128 + col]);
        else { int k = t - 128; Wt2[col * 128 + k] = f2bf(W2[(size_t)k * 128 + col]); }
    }
}

__global__ void count_deg_kernel(const int* __restrict__ dst, int E, int* __restrict__ deg) {
    int e = blockIdx.x * blockDim.x + threadIdx.x;
    if (e < E) atomicAdd(&deg[dst[e]], 1);
}

// block scans 1024 elements (256 threads x 4) -> rowcur = exclusive prefix
__global__ void scan_pass1(const int* __restrict__ deg, int n,
                           int* __restrict__ rowcur, int* __restrict__ bsums) {
    __shared__ int s[256];
    int tid = threadIdx.x;
    int base = blockIdx.x * 1024;
    int v[4];
    int mysum = 0;
#pragma unroll
    for (int j = 0; j < 4; ++j) {
        int idx = base + tid * 4 + j;
        v[j] = (idx < n) ? deg[idx] : 0;
        mysum += v[j];
    }
    s[tid] = mysum;
    __syncthreads();
    for (int off = 1; off < 256; off <<= 1) {
        int t = (tid >= off) ? s[tid - off] : 0;
        __syncthreads();
        s[tid] += t;
        __syncthreads();
    }
    int excl = s[tid] - mysum;
#pragma unroll
    for (int j = 0; j < 4; ++j) {
        int idx = base + tid * 4 + j;
        if (idx < n) rowcur[idx] = excl;
        excl += v[j];
    }
    if (tid == 255) bsums[blockIdx.x] = s[255];
}

// merged pass2+3: each block redoes the tiny nb-entry prefix in LDS; also dinv.
__global__ void scan_pass23(int* __restrict__ rowcur, const int* __restrict__ bsums,
                            const int* __restrict__ deg, float* __restrict__ dinv,
                            int n, int nb) {
    __shared__ int sm[64];
    __shared__ int pref[64];
    int tid = threadIdx.x;
    if (tid < 64) sm[tid] = (tid < nb) ? bsums[tid] : 0;
    __syncthreads();
    if (tid == 0) {
        int s = 0;
#pragma unroll 8
        for (int i = 0; i < 64; ++i) { pref[i] = s; s += sm[i]; }
    }
    __syncthreads();
    int add = pref[blockIdx.x];
    int base = blockIdx.x * 1024;
#pragma unroll
    for (int j = 0; j < 4; ++j) {
        int idx = base + tid * 4 + j;
        if (idx < n) {
            rowcur[idx] += add;
            dinv[idx] = rsqrtf((float)deg[idx] + 1.0f);
        }
    }
}

#if USE_FP8
#define G_STORE(outp, row, col, val) ((unsigned char*)(outp))[(size_t)(row) * 128 + (col)] = f2fp8(val)
#else
#define G_STORE(outp, row, col, val) ((unsigned short*)(outp))[(size_t)(row) * 128 + (col)] = f2bf(val)
#endif

// ---- merged: blocks [0,eb) fill CSR (single-array atomic cursor: rowcur
// becomes end-pointers); blocks [eb,eb+gb) run layer-1 GEMM (independent).
// GEMM: 4 waves/block, wave: 16 rows x 128 cols, K=128, mfma 16x16x32 bf16;
// A/B same (lane,elem)->k mapping; C/D: col=lane&15, row=(lane>>4)*4+reg.
__global__ __launch_bounds__(256) void csr_gemm1_kernel(const int* __restrict__ src,
                                                        const int* __restrict__ dst, int E,
                                                        int* __restrict__ rowcur,
                                                        int* __restrict__ csr,
                                                        const float* __restrict__ A,
                                                        const unsigned short* __restrict__ Wt,
                                                        const float* __restrict__ dinv,
                                                        void* __restrict__ out,
                                                        int n, int eb) {
    if (blockIdx.x < eb) {
        int e = blockIdx.x * 256 + threadIdx.x;
        if (e < E) {
            int pos = atomicAdd(&rowcur[dst[e]], 1);
            csr[pos] = src[e];
        }
        return;
    }
    int tile = blockIdx.x - eb;
    int tid = threadIdx.x;
    int l = tid & 63;
    int wid = tid >> 6;
    int rowbase = tile * 64 + wid * 16;
    int lc = l & 15;
    int kq = l >> 4;

    int arow = rowbase + lc; if (arow > n - 1) arow = n - 1;
    const float* Ap = A + (size_t)arow * 128 + kq * 8;
    const unsigned short* Wp = Wt + (size_t)lc * 128 + kq * 8;

    f32x4 acc[8];
#pragma unroll
    for (int c = 0; c < 8; ++c) acc[c] = (f32x4){0.f, 0.f, 0.f, 0.f};

#pragma unroll
    for (int ks = 0; ks < 4; ++ks) {
        float4 f0 = *(const float4*)(Ap + ks * 32);
        float4 f1 = *(const float4*)(Ap + ks * 32 + 4);
        bf16x8 a = f8_to_bf(f0, f1);
#pragma unroll
        for (int c = 0; c < 8; ++c) {
            bf16x8 b = *(const bf16x8*)(Wp + c * 2048 + ks * 32);
            acc[c] = __builtin_amdgcn_mfma_f32_16x16x32_bf16(a, b, acc[c], 0, 0, 0);
        }
    }

    int r0 = kq * 4;
    float s[4];
    int orow[4];
#pragma unroll
    for (int r = 0; r < 4; ++r) {
        orow[r] = rowbase + r0 + r;
        s[r] = (orow[r] < n) ? dinv[orow[r]] : 0.f;
    }
#pragma unroll
    for (int c = 0; c < 8; ++c) {
#pragma unroll
        for (int r = 0; r < 4; ++r) {
            if (orow[r] < n) G_STORE(out, orow[r], c * 16 + lc, acc[c][r] * s[r]);
        }
    }
}

// bf16-input GEMM (layer 2)
__global__ __launch_bounds__(256) void gemm_mfma_kernel(const unsigned short* __restrict__ A,
                                                        const unsigned short* __restrict__ Wt,
                                                        const float* __restrict__ dinv,
                                                        void* __restrict__ out,
                                                        int n) {
    int tid = threadIdx.x;
    int l = tid & 63;
    int wid = tid >> 6;
    int rowbase = blockIdx.x * 64 + wid * 16;
    int lc = l & 15;
    int kq = l >> 4;

    int arow = rowbase + lc; if (arow > n - 1) arow = n - 1;
    const unsigned short* Ap = A + (size_t)arow * 128 + kq * 8;
    const unsigned short* Wp = Wt + (size_t)lc * 128 + kq * 8;

    f32x4 acc[8];
#pragma unroll
    for (int c = 0; c < 8; ++c) acc[c] = (f32x4){0.f, 0.f, 0.f, 0.f};

#pragma unroll
    for (int ks = 0; ks < 4; ++ks) {
        bf16x8 a = *(const bf16x8*)(Ap + ks * 32);
#pragma unroll
        for (int c = 0; c < 8; ++c) {
            bf16x8 b = *(const bf16x8*)(Wp + c * 2048 + ks * 32);
            acc[c] = __builtin_amdgcn_mfma_f32_16x16x32_bf16(a, b, acc[c], 0, 0, 0);
        }
    }

    int r0 = kq * 4;
    float s[4];
    int orow[4];
#pragma unroll
    for (int r = 0; r < 4; ++r) {
        orow[r] = rowbase + r0 + r;
        s[r] = (orow[r] < n) ? dinv[orow[r]] : 0.f;
    }
#pragma unroll
    for (int c = 0; c < 8; ++c) {
#pragma unroll
        for (int r = 0; r < 4; ++r) {
            if (orow[r] < n) G_STORE(out, orow[r], c * 16 + lc, acc[c][r] * s[r]);
        }
    }
}

// ---- aggregate: out_h[i] = bf16( relu(dinv[i]*(sum_nbr g[src] + g[i]) + bias) )
// rowend[i] = end of segment i (rowcur after fill); beg = i ? rowend[i-1] : 0.
#if USE_FP8
// g fp8 rows (128 B). One wave/node: li=lane&15 owns uint2 (8 fp8 = 8 feats),
// quad=lane>>4 walks 4 neighbors/group; unrolled 2 groups (8 nbrs) in flight.
__global__ __launch_bounds__(256) void aggregate_kernel(const void* __restrict__ gv,
                                                        const int* __restrict__ rowend,
                                                        const int* __restrict__ csr,
                                                        const float* __restrict__ dinv,
                                                        const float* __restrict__ bias,
                                                        unsigned int* __restrict__ out, int n) {
    const uint2* __restrict__ g2 = (const uint2*)gv;  // row = 16 uint2
    int lane = threadIdx.x & 63;
    int node = (blockIdx.x * blockDim.x + threadIdx.x) >> 6;
    if (node >= n) return;
    int li = lane & 15, quad = lane >> 4;
    int beg = (node > 0) ? rowend[node - 1] : 0;
    int end = rowend[node];
    float a0 = 0.f, a1 = 0.f, a2 = 0.f, a3 = 0.f;
    float a4 = 0.f, a5 = 0.f, a6 = 0.f, a7 = 0.f;
    int e = beg;
    for (; e + 8 <= end; e += 8) {
        int i0 = csr[e + quad];
        int i1 = csr[e + 4 + quad];
        uint2 v = g2[(size_t)i0 * 16 + li];
        uint2 w = g2[(size_t)i1 * 16 + li];
        f32x2 p0 = __builtin_amdgcn_cvt_pk_f32_fp8(v.x, false);
        f32x2 p1 = __builtin_amdgcn_cvt_pk_f32_fp8(v.x, true);
        f32x2 p2 = __builtin_amdgcn_cvt_pk_f32_fp8(v.y, false);
        f32x2 p3 = __builtin_amdgcn_cvt_pk_f32_fp8(v.y, true);
        f32x2 q0 = __builtin_amdgcn_cvt_pk_f32_fp8(w.x, false);
        f32x2 q1 = __builtin_amdgcn_cvt_pk_f32_fp8(w.x, true);
        f32x2 q2 = __builtin_amdgcn_cvt_pk_f32_fp8(w.y, false);
        f32x2 q3 = __builtin_amdgcn_cvt_pk_f32_fp8(w.y, true);
        a0 += p0.x + q0.x; a1 += p0.y + q0.y; a2 += p1.x + q1.x; a3 += p1.y + q1.y;
        a4 += p2.x + q2.x; a5 += p2.y + q2.y; a6 += p3.x + q3.x; a7 += p3.y + q3.y;
    }
    if (e + 4 <= end) {
        uint2 v = g2[(size_t)csr[e + quad] * 16 + li];
        f32x2 p0 = __builtin_amdgcn_cvt_pk_f32_fp8(v.x, false);
        f32x2 p1 = __builtin_amdgcn_cvt_pk_f32_fp8(v.x, true);
        f32x2 p2 = __builtin_amdgcn_cvt_pk_f32_fp8(v.y, false);
        f32x2 p3 = __builtin_amdgcn_cvt_pk_f32_fp8(v.y, true);
        a0 += p0.x; a1 += p0.y; a2 += p1.x; a3 += p1.y;
        a4 += p2.x; a5 += p2.y; a6 += p3.x; a7 += p3.y;
        e += 4;
    }
    if (e + quad < end) {
        uint2 v = g2[(size_t)csr[e + quad] * 16 + li];
        f32x2 p0 = __builtin_amdgcn_cvt_pk_f32_fp8(v.x, false);
        f32x2 p1 = __builtin_amdgcn_cvt_pk_f32_fp8(v.x, true);
        f32x2 p2 = __builtin_amdgcn_cvt_pk_f32_fp8(v.y, false);
        f32x2 p3 = __builtin_amdgcn_cvt_pk_f32_fp8(v.y, true);
        a0 += p0.x; a1 += p0.y; a2 += p1.x; a3 += p1.y;
        a4 += p2.x; a5 += p2.y; a6 += p3.x; a7 += p3.y;
    }
    a0 += __shfl_xor(a0, 16, 64); a0 += __shfl_xor(a0, 32, 64);
    a1 += __shfl_xor(a1, 16, 64); a1 += __shfl_xor(a1, 32, 64);
    a2 += __shfl_xor(a2, 16, 64); a2 += __shfl_xor(a2, 32, 64);
    a3 += __shfl_xor(a3, 16, 64); a3 += __shfl_xor(a3, 32, 64);
    a4 += __shfl_xor(a4, 16, 64); a4 += __shfl_xor(a4, 32, 64);
    a5 += __shfl_xor(a5, 16, 64); a5 += __shfl_xor(a5, 32, 64);
    a6 += __shfl_xor(a6, 16, 64); a6 += __shfl_xor(a6, 32, 64);
    a7 += __shfl_xor(a7, 16, 64); a7 += __shfl_xor(a7, 32, 64);
    if (quad == 0) {
        uint2 sv = g2[(size_t)node * 16 + li];  // self loop
        f32x2 s0 = __builtin_amdgcn_cvt_pk_f32_fp8(sv.x, false);
        f32x2 s1 = __builtin_amdgcn_cvt_pk_f32_fp8(sv.x, true);
        f32x2 s2 = __builtin_amdgcn_cvt_pk_f32_fp8(sv.y, false);
        f32x2 s3 = __builtin_amdgcn_cvt_pk_f32_fp8(sv.y, true);
        float dv = dinv[node];
        float4 bl = ((const float4*)bias)[li * 2];
        float4 bh = ((const float4*)bias)[li * 2 + 1];
        float r0 = fmaxf(dv * (a0 + s0.x) + bl.x, 0.f);
        float r1 = fmaxf(dv * (a1 + s0.y) + bl.y, 0.f);
        float r2 = fmaxf(dv * (a2 + s1.x) + bl.z, 0.f);
        float r3 = fmaxf(dv * (a3 + s1.y) + bl.w, 0.f);
        float r4 = fmaxf(dv * (a4 + s2.x) + bh.x, 0.f);
        float r5 = fmaxf(dv * (a5 + s2.y) + bh.y, 0.f);
        float r6 = fmaxf(dv * (a6 + s3.x) + bh.z, 0.f);
        float r7 = fmaxf(dv * (a7 + s3.y) + bh.w, 0.f);
        uint4 o;
        o.x = pack2bf(r0, r1); o.y = pack2bf(r2, r3);
        o.z = pack2bf(r4, r5); o.w = pack2bf(r6, r7);
        ((uint4*)out)[(size_t)node * 16 + li] = o;
    }
}
#else
// bf16 fallback: li=lane&31 owns uint2 (4 feats), pair walks 2 neighbors.
__global__ __launch_bounds__(256) void aggregate_kernel(const void* __restrict__ gv,
                                                        const int* __restrict__ rowend,
                                                        const int* __restrict__ csr,
                                                        const float* __restrict__ dinv,
                                                        const float* __restrict__ bias,
                                                        unsigned int* __restrict__ out, int n) {
    const uint2* __restrict__ g2 = (const uint2*)gv;
    int lane = threadIdx.x & 63;
    int node = (blockIdx.x * blockDim.x + threadIdx.x) >> 6;
    if (node >= n) return;
    int li = lane & 31, pair = lane >> 5;
    int beg = (node > 0) ? rowend[node - 1] : 0;
    int end = rowend[node];
    float a0 = 0.f, a1 = 0.f, a2 = 0.f, a3 = 0.f;
    int e = beg;
    for (; e + 2 <= end; e += 2) {
        uint2 v = g2[(size_t)csr[e + pair] * 32 + li];
        a0 += bflo(v.x); a1 += bfhi(v.x);
        a2 += bflo(v.y); a3 += bfhi(v.y);
    }
    if (e + pair < end) {
        uint2 v = g2[(size_t)csr[e + pair] * 32 + li];
        a0 += bflo(v.x); a1 += bfhi(v.x);
        a2 += bflo(v.y); a3 += bfhi(v.y);
    }
    a0 += __shfl_xor(a0, 32, 64);
    a1 += __shfl_xor(a1, 32, 64);
    a2 += __shfl_xor(a2, 32, 64);
    a3 += __shfl_xor(a3, 32, 64);
    if (pair == 0) {
        uint2 sv = g2[(size_t)node * 32 + li];
        float dv = dinv[node];
        float4 b = ((const float4*)bias)[li];
        float r0 = fmaxf(dv * (a0 + bflo(sv.x)) + b.x, 0.f);
        float r1 = fmaxf(dv * (a1 + bfhi(sv.x)) + b.y, 0.f);
        float r2 = fmaxf(dv * (a2 + bflo(sv.y)) + b.z, 0.f);
        float r3 = fmaxf(dv * (a3 + bfhi(sv.y)) + b.w, 0.f);
        ((uint2*)out)[(size_t)node * 32 + li] = make_uint2(pack2bf(r0, r1), pack2bf(r2, r3));
    }
}
#endif

// stage 1: 64 graphs x POOL_SUB sub-units; 256-thread blocks, 4 units/block
// (64-thread subgroup per unit, 2 bf16 features per thread)
__global__ __launch_bounds__(256) void pool_partial_kernel(const unsigned int* __restrict__ h,
                                                           const int* __restrict__ batch, int n,
                                                           float* __restrict__ partial) {
    int unit = blockIdx.x * 4 + (threadIdx.x >> 6);
    int t = threadIdx.x & 63;
    int g = unit / POOL_SUB;
    int sub = unit % POOL_SUB;
    int lo = 0, hi = n;
    while (lo < hi) { int mid = (lo + hi) >> 1; if (batch[mid] < g) lo = mid + 1; else hi = mid; }
    int start = lo;
    hi = n;
    while (lo < hi) { int mid = (lo + hi) >> 1; if (batch[mid] < g + 1) lo = mid + 1; else hi = mid; }
    int end = lo;
    int len = end - start;
    int b0 = start + (int)((long long)len * sub / POOL_SUB);
    int b1 = start + (int)((long long)len * (sub + 1) / POOL_SUB);
    float ax = 0.f, ay = 0.f;
    int i = b0;
    for (; i + 4 <= b1; i += 4) {
        unsigned int v0 = h[(size_t)(i + 0) * 64 + t];
        unsigned int v1 = h[(size_t)(i + 1) * 64 + t];
        unsigned int v2 = h[(size_t)(i + 2) * 64 + t];
        unsigned int v3 = h[(size_t)(i + 3) * 64 + t];
        ax += bflo(v0) + bflo(v1) + bflo(v2) + bflo(v3);
        ay += bfhi(v0) + bfhi(v1) + bfhi(v2) + bfhi(v3);
    }
    for (; i < b1; ++i) {
        unsigned int v0 = h[(size_t)i * 64 + t];
        ax += bflo(v0);
        ay += bfhi(v0);
    }
    partial[(size_t)unit * 128 + 2 * t]     = ax;
    partial[(size_t)unit * 128 + 2 * t + 1] = ay;
}

// fused: pool finish (first 128 threads) + LSTM step + heads. 64 blocks x 256.
// gates order i,f,g,o ; f dead (c0=0), W_hh dead (h0=0).
__global__ __launch_bounds__(256) void pool_lstm_kernel(const float* __restrict__ partial,
                                                        const int* __restrict__ batch, int n,
                                                        const float* __restrict__ W_ih,
                                                        const float* __restrict__ b_ih,
                                                        const float* __restrict__ b_hh,
                                                        const float* __restrict__ Wm,
                                                        const float* __restrict__ bm,
                                                        const float* __restrict__ Wv,
                                                        const float* __restrict__ bv,
                                                        float* __restrict__ out) {
    __shared__ __align__(16) float p[128];
    __shared__ float redm[256];
    __shared__ float redv[256];
    int gph = blockIdx.x;
    int tid = threadIdx.x;
    if (tid < 128) {
        int lo = 0, hi = n;
        while (lo < hi) { int mid = (lo + hi) >> 1; if (batch[mid] < gph) lo = mid + 1; else hi = mid; }
        int start = lo;
        hi = n;
        while (lo < hi) { int mid = (lo + hi) >> 1; if (batch[mid] < gph + 1) lo = mid + 1; else hi = mid; }
        int end = lo;
        float acc = 0.f;
#pragma unroll
        for (int s = 0; s < POOL_SUB; ++s)
            acc += partial[(size_t)(gph * POOL_SUB + s) * 128 + tid];
        p[tid] = acc / fmaxf((float)(end - start), 1.0f);
    }
    __syncthreads();
    float gi = b_ih[tid] + b_hh[tid];
    float gg = b_ih[512 + tid] + b_hh[512 + tid];
    float go = b_ih[768 + tid] + b_hh[768 + tid];
    const float4* wi = (const float4*)(W_ih + (size_t)tid * 128);
    const float4* wg = (const float4*)(W_ih + (size_t)(512 + tid) * 128);
    const float4* wo = (const float4*)(W_ih + (size_t)(768 + tid) * 128);
    const float4* p4 = (const float4*)p;
#pragma unroll 8
    for (int k = 0; k < 32; ++k) {
        float4 xv = p4[k];
        float4 a = wi[k], bq = wg[k], cq = wo[k];
        gi += xv.x * a.x + xv.y * a.y + xv.z * a.z + xv.w * a.w;
        gg += xv.x * bq.x + xv.y * bq.y + xv.z * bq.z + xv.w * bq.w;
        go += xv.x * cq.x + xv.y * cq.y + xv.z * cq.z + xv.w * cq.w;
    }
    float iv = 1.f / (1.f + expf(-gi));
    float cv = iv * tanhf(gg);
    float ov = 1.f / (1.f + expf(-go));
    float hT = ov * tanhf(cv);
    redm[tid] = hT * Wm[tid];
    redv[tid] = hT * Wv[tid];
    __syncthreads();
    for (int s = 128; s > 0; s >>= 1) {
        if (tid < s) { redm[tid] += redm[tid + s]; redv[tid] += redv[tid + s]; }
        __syncthreads();
    }
    if (tid == 0) {
        out[gph] = redm[0] + bm[0];
        float xv = redv[0] + bv[0];
        out[64 + gph] = fmaxf(xv, 0.f) + log1pf(expf(-fabsf(xv)));  // stable softplus
    }
}

extern "C" void kernel_launch(void* const* d_in, const int* in_sizes, int n_in,
                              void* d_out, int out_size, void* d_ws, size_t ws_size,
                              hipStream_t stream) {
    const float* x     = (const float*)d_in[0];
    const int*   edge  = (const int*)d_in[1];
    const int*   batch = (const int*)d_in[2];
    const float* W1    = (const float*)d_in[3];
    const float* b1    = (const float*)d_in[4];
    const float* W2    = (const float*)d_in[5];
    const float* b2    = (const float*)d_in[6];
    const float* W_ih  = (const float*)d_in[7];
    /* d_in[8] = W_hh: dead (h0 = 0) */
    const float* b_ih  = (const float*)d_in[9];
    const float* b_hh  = (const float*)d_in[10];
    const float* Wm    = (const float*)d_in[11];
    const float* bm    = (const float*)d_in[12];
    const float* Wv    = (const float*)d_in[13];
    const float* bv    = (const float*)d_in[14];
    float* out = (float*)d_out;

    const int N = in_sizes[0] / 128;
    const int E = in_sizes[1] / 2;
    const int* srcIdx = edge;      // edge_index[0]
    const int* dstIdx = edge + E;  // edge_index[1]

    char* ws = (char*)d_ws;
    size_t off = 0;
    const size_t gB = (size_t)N * 64 * sizeof(unsigned int);  // worst case (bf16)
    void* gbuf = (void*)(ws + off); off += gB;
    unsigned int* hbuf = (unsigned int*)(ws + off); off += gB;
    int* deg    = (int*)(ws + off);   off += (size_t)N * sizeof(int);
    int* rowcur = (int*)(ws + off);   off += (size_t)(N + 1) * sizeof(int);
    off = (off + 255) & ~(size_t)255;
    int* bsums  = (int*)(ws + off);   off += 512;
    int* csr    = (int*)(ws + off);   off += (size_t)E * sizeof(int);
    off = (off + 255) & ~(size_t)255;
    float* dinv = (float*)(ws + off); off += (size_t)N * sizeof(float);
    off = (off + 255) & ~(size_t)255;
    unsigned short* Wt1 = (unsigned short*)(ws + off); off += 128 * 128 * sizeof(unsigned short);
    unsigned short* Wt2 = (unsigned short*)(ws + off); off += 128 * 128 * sizeof(unsigned short);
    off = (off + 255) & ~(size_t)255;
    float* partial = (float*)(ws + off); off += (size_t)64 * POOL_SUB * 128 * sizeof(float);

    // prep: zero deg and convert W1/W2 to bf16-transposed in one launch
    int zwords = N;
    int zb = (zwords + 255) / 256;
    prep_kernel<<<zb + 128, 256, 0, stream>>>(deg, zwords, W1, W2, Wt1, Wt2, zb);

    int eb = (E + 255) / 256;
    count_deg_kernel<<<eb, 256, 0, stream>>>(dstIdx, E, deg);

    int nb = (N + 1023) / 1024;  // 49 for N=50000 (<=64 required by scan)
    scan_pass1<<<nb, 256, 0, stream>>>(deg, N, rowcur, bsums);
    scan_pass23<<<nb, 256, 0, stream>>>(rowcur, bsums, deg, dinv, N, nb);

    int gb = (N + 63) / 64;  // GEMM blocks (4 waves x 16 rows)
    int ab = (N + 3) / 4;    // aggregate blocks (4 nodes/block)

    // CSR fill (rowcur -> end pointers) || layer-1 GEMM (merged launch)
    csr_gemm1_kernel<<<eb + gb, 256, 0, stream>>>(srcIdx, dstIdx, E, rowcur, csr,
                                                  x, Wt1, dinv, gbuf, N, eb);
    aggregate_kernel<<<ab, 256, 0, stream>>>(gbuf, rowcur, csr, dinv, b1, hbuf, N);
    // layer 2
    gemm_mfma_kernel<<<gb, 256, 0, stream>>>((const unsigned short*)hbuf, Wt2, dinv, gbuf, N);
    aggregate_kernel<<<ab, 256, 0, stream>>>(gbuf, rowcur, csr, dinv, b2, hbuf, N);

    // pooling + fused finish+LSTM+heads
    pool_partial_kernel<<<(64 * POOL_SUB) / 4, 256, 0, stream>>>(hbuf, batch, N, partial);
    pool_lstm_kernel<<<64, 256, 0, stream>>>(partial, batch, N, W_ih, b_ih, b_hh, Wm, bm, Wv, bv, out);
}

// Round 21
// 203.149 us; speedup vs baseline: 1.0315x; 1.0315x over previous
//
#include <hip/hip_runtime.h>
#include <hip/hip_bf16.h>
#include <math.h>

// ---------------------------------------------------------------------------
// GCN(2 layers, fused norm) -> mean-pool -> LSTM step (h0=c0=0) -> heads
// GEMMs via bf16 MFMA (f32 accum). Gather buffer fp8-e4m3 (HW cvt), h bf16,
// all accumulation f32. 10 stream-ordered launches (csr||gemm1 merged;
// cooperative mega-kernel measured 4-6x WORSE: grid.sync ~120us/barrier;
// single-array CSR cursor measured WORSE: lengthens atomic critical section).
// ---------------------------------------------------------------------------

#define POOL_SUB 32

#if __has_builtin(__builtin_amdgcn_cvt_pk_f32_fp8) && __has_builtin(__builtin_amdgcn_cvt_pk_fp8_f32)
#define USE_FP8 1
#else
#define USE_FP8 0
#endif

typedef __attribute__((ext_vector_type(8))) short bf16x8;
typedef __attribute__((ext_vector_type(4))) float f32x4;
typedef __attribute__((ext_vector_type(2))) float f32x2;

static __device__ __forceinline__ unsigned short f2bf(float f) {
    union { float f; unsigned int u; } v; v.f = f;
    unsigned int u = v.u;
    unsigned int r = u + 0x7FFFu + ((u >> 16) & 1u);  // RNE
    return (unsigned short)(r >> 16);
}
static __device__ __forceinline__ unsigned int pack2bf(float lo, float hi) {
    return (unsigned int)f2bf(lo) | ((unsigned int)f2bf(hi) << 16);
}
static __device__ __forceinline__ float bflo(unsigned int v) {
    union { unsigned int u; float f; } w; w.u = v << 16; return w.f;
}
static __device__ __forceinline__ float bfhi(unsigned int v) {
    union { unsigned int u; float f; } w; w.u = v & 0xFFFF0000u; return w.f;
}
static __device__ __forceinline__ bf16x8 f8_to_bf(float4 f0, float4 f1) {
    union { unsigned int u[4]; bf16x8 v; } r;
    r.u[0] = pack2bf(f0.x, f0.y);
    r.u[1] = pack2bf(f0.z, f0.w);
    r.u[2] = pack2bf(f1.x, f1.y);
    r.u[3] = pack2bf(f1.z, f1.w);
    return r.v;
}
#if USE_FP8
static __device__ __forceinline__ unsigned char f2fp8(float f) {
    return (unsigned char)(__builtin_amdgcn_cvt_pk_fp8_f32(f, f, 0, false) & 0xFF);
}
#endif

// blocks [0,zb): zero deg+cursor; blocks [zb,zb+128): W1/W2 -> bf16 transposed
__global__ __launch_bounds__(256) void prep_kernel(int* __restrict__ zp, int zwords,
                                                   const float* __restrict__ W1,
                                                   const float* __restrict__ W2,
                                                   unsigned short* __restrict__ Wt1,
                                                   unsigned short* __restrict__ Wt2, int zb) {
    int b = blockIdx.x;
    int t = threadIdx.x;
    if (b < zb) {
        int i = b * 256 + t;
        if (i < zwords) zp[i] = 0;
    } else {
        int col = b - zb;  // 0..127
        if (t < 128) Wt1[col * 128 + t] = f2bf(W1[(size_t)t * 128 + col]);
        else { int k = t - 128; Wt2[col * 128 + k] = f2bf(W2[(size_t)k * 128 + col]); }
    }
}

__global__ void count_deg_kernel(const int* __restrict__ dst, int E, int* __restrict__ deg) {
    int e = blockIdx.x * blockDim.x + threadIdx.x;
    if (e < E) atomicAdd(&deg[dst[e]], 1);
}

// block scans 1024 elements (256 threads x 4)
__global__ void scan_pass1(const int* __restrict__ deg, int n,
                           int* __restrict__ rowptr, int* __restrict__ bsums) {
    __shared__ int s[256];
    int tid = threadIdx.x;
    int base = blockIdx.x * 1024;
    int v[4];
    int mysum = 0;
#pragma unroll
    for (int j = 0; j < 4; ++j) {
        int idx = base + tid * 4 + j;
        v[j] = (idx < n) ? deg[idx] : 0;
        mysum += v[j];
    }
    s[tid] = mysum;
    __syncthreads();
    for (int off = 1; off < 256; off <<= 1) {
        int t = (tid >= off) ? s[tid - off] : 0;
        __syncthreads();
        s[tid] += t;
        __syncthreads();
    }
    int excl = s[tid] - mysum;
#pragma unroll
    for (int j = 0; j < 4; ++j) {
        int idx = base + tid * 4 + j;
        if (idx < n) rowptr[idx] = excl;
        excl += v[j];
    }
    if (tid == 255) bsums[blockIdx.x] = s[255];
}

// merged pass2+3: each block redoes the tiny nb-entry prefix in LDS; also dinv.
__global__ void scan_pass23(int* __restrict__ rowptr, const int* __restrict__ bsums,
                            const int* __restrict__ deg, float* __restrict__ dinv,
                            int n, int nb) {
    __shared__ int sm[64];
    __shared__ int pref[65];
    int tid = threadIdx.x;
    if (tid < 64) sm[tid] = (tid < nb) ? bsums[tid] : 0;
    __syncthreads();
    if (tid == 0) {
        int s = 0;
#pragma unroll 8
        for (int i = 0; i < 64; ++i) { pref[i] = s; s += sm[i]; }
        pref[64] = s;
    }
    __syncthreads();
    int add = pref[blockIdx.x];
    int base = blockIdx.x * 1024;
#pragma unroll
    for (int j = 0; j < 4; ++j) {
        int idx = base + tid * 4 + j;
        if (idx < n) {
            rowptr[idx] += add;
            dinv[idx] = rsqrtf((float)deg[idx] + 1.0f);
        }
    }
    if (blockIdx.x == 0 && tid == 0) rowptr[n] = pref[64];
}

#if USE_FP8
#define G_STORE(outp, row, col, val) ((unsigned char*)(outp))[(size_t)(row) * 128 + (col)] = f2fp8(val)
#else
#define G_STORE(outp, row, col, val) ((unsigned short*)(outp))[(size_t)(row) * 128 + (col)] = f2bf(val)
#endif

// ---- merged: blocks [0,eb) fill CSR; blocks [eb,eb+gb) run layer-1 GEMM.
// Both depend only on scan output (rowptr/dinv/cursor) -> safe in one launch.
// GEMM: 4 waves/block, wave: 16 rows x 128 cols, K=128, mfma 16x16x32 bf16;
// A/B same (lane,elem)->k mapping; C/D: col=lane&15, row=(lane>>4)*4+reg.
__global__ __launch_bounds__(256) void csr_gemm1_kernel(const int* __restrict__ src,
                                                        const int* __restrict__ dst, int E,
                                                        const int* __restrict__ rowptr,
                                                        int* __restrict__ cursor,
                                                        int* __restrict__ csr,
                                                        const float* __restrict__ A,
                                                        const unsigned short* __restrict__ Wt,
                                                        const float* __restrict__ dinv,
                                                        void* __restrict__ out,
                                                        int n, int eb) {
    if (blockIdx.x < eb) {
        int e = blockIdx.x * 256 + threadIdx.x;
        if (e < E) {
            int d = dst[e];
            int pos = rowptr[d] + atomicAdd(&cursor[d], 1);
            csr[pos] = src[e];
        }
        return;
    }
    int tile = blockIdx.x - eb;
    int tid = threadIdx.x;
    int l = tid & 63;
    int wid = tid >> 6;
    int rowbase = tile * 64 + wid * 16;
    int lc = l & 15;
    int kq = l >> 4;

    int arow = rowbase + lc; if (arow > n - 1) arow = n - 1;
    const float* Ap = A + (size_t)arow * 128 + kq * 8;
    const unsigned short* Wp = Wt + (size_t)lc * 128 + kq * 8;

    f32x4 acc[8];
#pragma unroll
    for (int c = 0; c < 8; ++c) acc[c] = (f32x4){0.f, 0.f, 0.f, 0.f};

#pragma unroll
    for (int ks = 0; ks < 4; ++ks) {
        float4 f0 = *(const float4*)(Ap + ks * 32);
        float4 f1 = *(const float4*)(Ap + ks * 32 + 4);
        bf16x8 a = f8_to_bf(f0, f1);
#pragma unroll
        for (int c = 0; c < 8; ++c) {
            bf16x8 b = *(const bf16x8*)(Wp + c * 2048 + ks * 32);
            acc[c] = __builtin_amdgcn_mfma_f32_16x16x32_bf16(a, b, acc[c], 0, 0, 0);
        }
    }

    int r0 = kq * 4;
    float s[4];
    int orow[4];
#pragma unroll
    for (int r = 0; r < 4; ++r) {
        orow[r] = rowbase + r0 + r;
        s[r] = (orow[r] < n) ? dinv[orow[r]] : 0.f;
    }
#pragma unroll
    for (int c = 0; c < 8; ++c) {
#pragma unroll
        for (int r = 0; r < 4; ++r) {
            if (orow[r] < n) G_STORE(out, orow[r], c * 16 + lc, acc[c][r] * s[r]);
        }
    }
}

// bf16-input GEMM (layer 2)
__global__ __launch_bounds__(256) void gemm_mfma_kernel(const unsigned short* __restrict__ A,
                                                        const unsigned short* __restrict__ Wt,
                                                        const float* __restrict__ dinv,
                                                        void* __restrict__ out,
                                                        int n) {
    int tid = threadIdx.x;
    int l = tid & 63;
    int wid = tid >> 6;
    int rowbase = blockIdx.x * 64 + wid * 16;
    int lc = l & 15;
    int kq = l >> 4;

    int arow = rowbase + lc; if (arow > n - 1) arow = n - 1;
    const unsigned short* Ap = A + (size_t)arow * 128 + kq * 8;
    const unsigned short* Wp = Wt + (size_t)lc * 128 + kq * 8;

    f32x4 acc[8];
#pragma unroll
    for (int c = 0; c < 8; ++c) acc[c] = (f32x4){0.f, 0.f, 0.f, 0.f};

#pragma unroll
    for (int ks = 0; ks < 4; ++ks) {
        bf16x8 a = *(const bf16x8*)(Ap + ks * 32);
#pragma unroll
        for (int c = 0; c < 8; ++c) {
            bf16x8 b = *(const bf16x8*)(Wp + c * 2048 + ks * 32);
            acc[c] = __builtin_amdgcn_mfma_f32_16x16x32_bf16(a, b, acc[c], 0, 0, 0);
        }
    }

    int r0 = kq * 4;
    float s[4];
    int orow[4];
#pragma unroll
    for (int r = 0; r < 4; ++r) {
        orow[r] = rowbase + r0 + r;
        s[r] = (orow[r] < n) ? dinv[orow[r]] : 0.f;
    }
#pragma unroll
    for (int c = 0; c < 8; ++c) {
#pragma unroll
        for (int r = 0; r < 4; ++r) {
            if (orow[r] < n) G_STORE(out, orow[r], c * 16 + lc, acc[c][r] * s[r]);
        }
    }
}

// ---- aggregate: out_h[i] = bf16( relu(dinv[i]*(sum_nbr g[src] + g[i]) + bias) )
#if USE_FP8
// g fp8 rows (128 B). One wave/node: li=lane&15 owns uint2 (8 fp8 = 8 feats),
// quad=lane>>4 walks 4 neighbors/group; unrolled 2 groups (8 nbrs) in flight.
__global__ __launch_bounds__(256) void aggregate_kernel(const void* __restrict__ gv,
                                                        const int* __restrict__ rowptr,
                                                        const int* __restrict__ csr,
                                                        const float* __restrict__ dinv,
                                                        const float* __restrict__ bias,
                                                        unsigned int* __restrict__ out, int n) {
    const uint2* __restrict__ g2 = (const uint2*)gv;  // row = 16 uint2
    int lane = threadIdx.x & 63;
    int node = (blockIdx.x * blockDim.x + threadIdx.x) >> 6;
    if (node >= n) return;
    int li = lane & 15, quad = lane >> 4;
    int beg = rowptr[node], end = rowptr[node + 1];
    float a0 = 0.f, a1 = 0.f, a2 = 0.f, a3 = 0.f;
    float a4 = 0.f, a5 = 0.f, a6 = 0.f, a7 = 0.f;
    int e = beg;
    for (; e + 8 <= end; e += 8) {
        int i0 = csr[e + quad];
        int i1 = csr[e + 4 + quad];
        uint2 v = g2[(size_t)i0 * 16 + li];
        uint2 w = g2[(size_t)i1 * 16 + li];
        f32x2 p0 = __builtin_amdgcn_cvt_pk_f32_fp8(v.x, false);
        f32x2 p1 = __builtin_amdgcn_cvt_pk_f32_fp8(v.x, true);
        f32x2 p2 = __builtin_amdgcn_cvt_pk_f32_fp8(v.y, false);
        f32x2 p3 = __builtin_amdgcn_cvt_pk_f32_fp8(v.y, true);
        f32x2 q0 = __builtin_amdgcn_cvt_pk_f32_fp8(w.x, false);
        f32x2 q1 = __builtin_amdgcn_cvt_pk_f32_fp8(w.x, true);
        f32x2 q2 = __builtin_amdgcn_cvt_pk_f32_fp8(w.y, false);
        f32x2 q3 = __builtin_amdgcn_cvt_pk_f32_fp8(w.y, true);
        a0 += p0.x + q0.x; a1 += p0.y + q0.y; a2 += p1.x + q1.x; a3 += p1.y + q1.y;
        a4 += p2.x + q2.x; a5 += p2.y + q2.y; a6 += p3.x + q3.x; a7 += p3.y + q3.y;
    }
    if (e + 4 <= end) {
        uint2 v = g2[(size_t)csr[e + quad] * 16 + li];
        f32x2 p0 = __builtin_amdgcn_cvt_pk_f32_fp8(v.x, false);
        f32x2 p1 = __builtin_amdgcn_cvt_pk_f32_fp8(v.x, true);
        f32x2 p2 = __builtin_amdgcn_cvt_pk_f32_fp8(v.y, false);
        f32x2 p3 = __builtin_amdgcn_cvt_pk_f32_fp8(v.y, true);
        a0 += p0.x; a1 += p0.y; a2 += p1.x; a3 += p1.y;
        a4 += p2.x; a5 += p2.y; a6 += p3.x; a7 += p3.y;
        e += 4;
    }
    if (e + quad < end) {
        uint2 v = g2[(size_t)csr[e + quad] * 16 + li];
        f32x2 p0 = __builtin_amdgcn_cvt_pk_f32_fp8(v.x, false);
        f32x2 p1 = __builtin_amdgcn_cvt_pk_f32_fp8(v.x, true);
        f32x2 p2 = __builtin_amdgcn_cvt_pk_f32_fp8(v.y, false);
        f32x2 p3 = __builtin_amdgcn_cvt_pk_f32_fp8(v.y, true);
        a0 += p0.x; a1 += p0.y; a2 += p1.x; a3 += p1.y;
        a4 += p2.x; a5 += p2.y; a6 += p3.x; a7 += p3.y;
    }
    a0 += __shfl_xor(a0, 16, 64); a0 += __shfl_xor(a0, 32, 64);
    a1 += __shfl_xor(a1, 16, 64); a1 += __shfl_xor(a1, 32, 64);
    a2 += __shfl_xor(a2, 16, 64); a2 += __shfl_xor(a2, 32, 64);
    a3 += __shfl_xor(a3, 16, 64); a3 += __shfl_xor(a3, 32, 64);
    a4 += __shfl_xor(a4, 16, 64); a4 += __shfl_xor(a4, 32, 64);
    a5 += __shfl_xor(a5, 16, 64); a5 += __shfl_xor(a5, 32, 64);
    a6 += __shfl_xor(a6, 16, 64); a6 += __shfl_xor(a6, 32, 64);
    a7 += __shfl_xor(a7, 16, 64); a7 += __shfl_xor(a7, 32, 64);
    if (quad == 0) {
        uint2 sv = g2[(size_t)node * 16 + li];  // self loop
        f32x2 s0 = __builtin_amdgcn_cvt_pk_f32_fp8(sv.x, false);
        f32x2 s1 = __builtin_amdgcn_cvt_pk_f32_fp8(sv.x, true);
        f32x2 s2 = __builtin_amdgcn_cvt_pk_f32_fp8(sv.y, false);
        f32x2 s3 = __builtin_amdgcn_cvt_pk_f32_fp8(sv.y, true);
        float dv = dinv[node];
        float4 bl = ((const float4*)bias)[li * 2];
        float4 bh = ((const float4*)bias)[li * 2 + 1];
        float r0 = fmaxf(dv * (a0 + s0.x) + bl.x, 0.f);
        float r1 = fmaxf(dv * (a1 + s0.y) + bl.y, 0.f);
        float r2 = fmaxf(dv * (a2 + s1.x) + bl.z, 0.f);
        float r3 = fmaxf(dv * (a3 + s1.y) + bl.w, 0.f);
        float r4 = fmaxf(dv * (a4 + s2.x) + bh.x, 0.f);
        float r5 = fmaxf(dv * (a5 + s2.y) + bh.y, 0.f);
        float r6 = fmaxf(dv * (a6 + s3.x) + bh.z, 0.f);
        float r7 = fmaxf(dv * (a7 + s3.y) + bh.w, 0.f);
        uint4 o;
        o.x = pack2bf(r0, r1); o.y = pack2bf(r2, r3);
        o.z = pack2bf(r4, r5); o.w = pack2bf(r6, r7);
        ((uint4*)out)[(size_t)node * 16 + li] = o;
    }
}
#else
// bf16 fallback: li=lane&31 owns uint2 (4 feats), pair walks 2 neighbors.
__global__ __launch_bounds__(256) void aggregate_kernel(const void* __restrict__ gv,
                                                        const int* __restrict__ rowptr,
                                                        const int* __restrict__ csr,
                                                        const float* __restrict__ dinv,
                                                        const float* __restrict__ bias,
                                                        unsigned int* __restrict__ out, int n) {
    const uint2* __restrict__ g2 = (const uint2*)gv;
    int lane = threadIdx.x & 63;
    int node = (blockIdx.x * blockDim.x + threadIdx.x) >> 6;
    if (node >= n) return;
    int li = lane & 31, pair = lane >> 5;
    int beg = rowptr[node], end = rowptr[node + 1];
    float a0 = 0.f, a1 = 0.f, a2 = 0.f, a3 = 0.f;
    int e = beg;
    for (; e + 2 <= end; e += 2) {
        uint2 v = g2[(size_t)csr[e + pair] * 32 + li];
        a0 += bflo(v.x); a1 += bfhi(v.x);
        a2 += bflo(v.y); a3 += bfhi(v.y);
    }
    if (e + pair < end) {
        uint2 v = g2[(size_t)csr[e + pair] * 32 + li];
        a0 += bflo(v.x); a1 += bfhi(v.x);
        a2 += bflo(v.y); a3 += bfhi(v.y);
    }
    a0 += __shfl_xor(a0, 32, 64);
    a1 += __shfl_xor(a1, 32, 64);
    a2 += __shfl_xor(a2, 32, 64);
    a3 += __shfl_xor(a3, 32, 64);
    if (pair == 0) {
        uint2 sv = g2[(size_t)node * 32 + li];
        float dv = dinv[node];
        float4 b = ((const float4*)bias)[li];
        float r0 = fmaxf(dv * (a0 + bflo(sv.x)) + b.x, 0.f);
        float r1 = fmaxf(dv * (a1 + bfhi(sv.x)) + b.y, 0.f);
        float r2 = fmaxf(dv * (a2 + bflo(sv.y)) + b.z, 0.f);
        float r3 = fmaxf(dv * (a3 + bfhi(sv.y)) + b.w, 0.f);
        ((uint2*)out)[(size_t)node * 32 + li] = make_uint2(pack2bf(r0, r1), pack2bf(r2, r3));
    }
}
#endif

// stage 1: 64 graphs x POOL_SUB sub-units; 256-thread blocks, 4 units/block
// (64-thread subgroup per unit, 2 bf16 features per thread)
__global__ __launch_bounds__(256) void pool_partial_kernel(const unsigned int* __restrict__ h,
                                                           const int* __restrict__ batch, int n,
                                                           float* __restrict__ partial) {
    int unit = blockIdx.x * 4 + (threadIdx.x >> 6);
    int t = threadIdx.x & 63;
    int g = unit / POOL_SUB;
    int sub = unit % POOL_SUB;
    int lo = 0, hi = n;
    while (lo < hi) { int mid = (lo + hi) >> 1; if (batch[mid] < g) lo = mid + 1; else hi = mid; }
    int start = lo;
    hi = n;
    while (lo < hi) { int mid = (lo + hi) >> 1; if (batch[mid] < g + 1) lo = mid + 1; else hi = mid; }
    int end = lo;
    int len = end - start;
    int b0 = start + (int)((long long)len * sub / POOL_SUB);
    int b1 = start + (int)((long long)len * (sub + 1) / POOL_SUB);
    float ax = 0.f, ay = 0.f;
    int i = b0;
    for (; i + 4 <= b1; i += 4) {
        unsigned int v0 = h[(size_t)(i + 0) * 64 + t];
        unsigned int v1 = h[(size_t)(i + 1) * 64 + t];
        unsigned int v2 = h[(size_t)(i + 2) * 64 + t];
        unsigned int v3 = h[(size_t)(i + 3) * 64 + t];
        ax += bflo(v0) + bflo(v1) + bflo(v2) + bflo(v3);
        ay += bfhi(v0) + bfhi(v1) + bfhi(v2) + bfhi(v3);
    }
    for (; i < b1; ++i) {
        unsigned int v0 = h[(size_t)i * 64 + t];
        ax += bflo(v0);
        ay += bfhi(v0);
    }
    partial[(size_t)unit * 128 + 2 * t]     = ax;
    partial[(size_t)unit * 128 + 2 * t + 1] = ay;
}

// fused: pool finish (first 128 threads) + LSTM step + heads. 64 blocks x 256.
// gates order i,f,g,o ; f dead (c0=0), W_hh dead (h0=0).
__global__ __launch_bounds__(256) void pool_lstm_kernel(const float* __restrict__ partial,
                                                        const int* __restrict__ batch, int n,
                                                        const float* __restrict__ W_ih,
                                                        const float* __restrict__ b_ih,
                                                        const float* __restrict__ b_hh,
                                                        const float* __restrict__ Wm,
                                                        const float* __restrict__ bm,
                                                        const float* __restrict__ Wv,
                                                        const float* __restrict__ bv,
                                                        float* __restrict__ out) {
    __shared__ __align__(16) float p[128];
    __shared__ float redm[256];
    __shared__ float redv[256];
    int gph = blockIdx.x;
    int tid = threadIdx.x;
    if (tid < 128) {
        int lo = 0, hi = n;
        while (lo < hi) { int mid = (lo + hi) >> 1; if (batch[mid] < gph) lo = mid + 1; else hi = mid; }
        int start = lo;
        hi = n;
        while (lo < hi) { int mid = (lo + hi) >> 1; if (batch[mid] < gph + 1) lo = mid + 1; else hi = mid; }
        int end = lo;
        float acc = 0.f;
#pragma unroll
        for (int s = 0; s < POOL_SUB; ++s)
            acc += partial[(size_t)(gph * POOL_SUB + s) * 128 + tid];
        p[tid] = acc / fmaxf((float)(end - start), 1.0f);
    }
    __syncthreads();
    float gi = b_ih[tid] + b_hh[tid];
    float gg = b_ih[512 + tid] + b_hh[512 + tid];
    float go = b_ih[768 + tid] + b_hh[768 + tid];
    const float4* wi = (const float4*)(W_ih + (size_t)tid * 128);
    const float4* wg = (const float4*)(W_ih + (size_t)(512 + tid) * 128);
    const float4* wo = (const float4*)(W_ih + (size_t)(768 + tid) * 128);
    const float4* p4 = (const float4*)p;
#pragma unroll 8
    for (int k = 0; k < 32; ++k) {
        float4 xv = p4[k];
        float4 a = wi[k], bq = wg[k], cq = wo[k];
        gi += xv.x * a.x + xv.y * a.y + xv.z * a.z + xv.w * a.w;
        gg += xv.x * bq.x + xv.y * bq.y + xv.z * bq.z + xv.w * bq.w;
        go += xv.x * cq.x + xv.y * cq.y + xv.z * cq.z + xv.w * cq.w;
    }
    float iv = 1.f / (1.f + expf(-gi));
    float cv = iv * tanhf(gg);
    float ov = 1.f / (1.f + expf(-go));
    float hT = ov * tanhf(cv);
    redm[tid] = hT * Wm[tid];
    redv[tid] = hT * Wv[tid];
    __syncthreads();
    for (int s = 128; s > 0; s >>= 1) {
        if (tid < s) { redm[tid] += redm[tid + s]; redv[tid] += redv[tid + s]; }
        __syncthreads();
    }
    if (tid == 0) {
        out[gph] = redm[0] + bm[0];
        float xv = redv[0] + bv[0];
        out[64 + gph] = fmaxf(xv, 0.f) + log1pf(expf(-fabsf(xv)));  // stable softplus
    }
}

extern "C" void kernel_launch(void* const* d_in, const int* in_sizes, int n_in,
                              void* d_out, int out_size, void* d_ws, size_t ws_size,
                              hipStream_t stream) {
    const float* x     = (const float*)d_in[0];
    const int*   edge  = (const int*)d_in[1];
    const int*   batch = (const int*)d_in[2];
    const float* W1    = (const float*)d_in[3];
    const float* b1    = (const float*)d_in[4];
    const float* W2    = (const float*)d_in[5];
    const float* b2    = (const float*)d_in[6];
    const float* W_ih  = (const float*)d_in[7];
    /* d_in[8] = W_hh: dead (h0 = 0) */
    const float* b_ih  = (const float*)d_in[9];
    const float* b_hh  = (const float*)d_in[10];
    const float* Wm    = (const float*)d_in[11];
    const float* bm    = (const float*)d_in[12];
    const float* Wv    = (const float*)d_in[13];
    const float* bv    = (const float*)d_in[14];
    float* out = (float*)d_out;

    const int N = in_sizes[0] / 128;
    const int E = in_sizes[1] / 2;
    const int* srcIdx = edge;      // edge_index[0]
    const int* dstIdx = edge + E;  // edge_index[1]

    char* ws = (char*)d_ws;
    size_t off = 0;
    const size_t gB = (size_t)N * 64 * sizeof(unsigned int);  // worst case (bf16)
    void* gbuf = (void*)(ws + off); off += gB;
    unsigned int* hbuf = (unsigned int*)(ws + off); off += gB;
    int* deg    = (int*)(ws + off);   off += (size_t)N * sizeof(int);
    int* cursor = (int*)(ws + off);   off += (size_t)N * sizeof(int);  // adjacent to deg
    int* rowptr = (int*)(ws + off);   off += (size_t)(N + 1) * sizeof(int);
    off = (off + 255) & ~(size_t)255;
    int* bsums  = (int*)(ws + off);   off += 512;
    int* csr    = (int*)(ws + off);   off += (size_t)E * sizeof(int);
    off = (off + 255) & ~(size_t)255;
    float* dinv = (float*)(ws + off); off += (size_t)N * sizeof(float);
    off = (off + 255) & ~(size_t)255;
    unsigned short* Wt1 = (unsigned short*)(ws + off); off += 128 * 128 * sizeof(unsigned short);
    unsigned short* Wt2 = (unsigned short*)(ws + off); off += 128 * 128 * sizeof(unsigned short);
    off = (off + 255) & ~(size_t)255;
    float* partial = (float*)(ws + off); off += (size_t)64 * POOL_SUB * 128 * sizeof(float);

    // prep: zero deg+cursor and convert W1/W2 to bf16-transposed in one launch
    int zwords = 2 * N;
    int zb = (zwords + 255) / 256;
    prep_kernel<<<zb + 128, 256, 0, stream>>>(deg, zwords, W1, W2, Wt1, Wt2, zb);

    int eb = (E + 255) / 256;
    count_deg_kernel<<<eb, 256, 0, stream>>>(dstIdx, E, deg);

    int nb = (N + 1023) / 1024;  // 49 for N=50000 (<=64 required by scan)
    scan_pass1<<<nb, 256, 0, stream>>>(deg, N, rowptr, bsums);
    scan_pass23<<<nb, 256, 0, stream>>>(rowptr, bsums, deg, dinv, N, nb);

    int gb = (N + 63) / 64;  // GEMM blocks (4 waves x 16 rows)
    int ab = (N + 3) / 4;    // aggregate blocks (4 nodes/block)

    // CSR fill || layer-1 GEMM (independent, merged launch)
    csr_gemm1_kernel<<<eb + gb, 256, 0, stream>>>(srcIdx, dstIdx, E, rowptr, cursor, csr,
                                                  x, Wt1, dinv, gbuf, N, eb);
    aggregate_kernel<<<ab, 256, 0, stream>>>(gbuf, rowptr, csr, dinv, b1, hbuf, N);
    // layer 2
    gemm_mfma_kernel<<<gb, 256, 0, stream>>>((const unsigned short*)hbuf, Wt2, dinv, gbuf, N);
    aggregate_kernel<<<ab, 256, 0, stream>>>(gbuf, rowptr, csr, dinv, b2, hbuf, N);

    // pooling + fused finish+LSTM+heads
    pool_partial_kernel<<<(64 * POOL_SUB) / 4, 256, 0, stream>>>(hbuf, batch, N, partial);
    pool_lstm_kernel<<<64, 256, 0, stream>>>(partial, batch, N, W_ih, b_ih, b_hh, Wm, bm, Wv, bv, out);
}